// Round 5
// baseline (292.033 us; speedup 1.0000x reference)
//
#include <hip/hip_runtime.h>

#define TPB 256
#define GTPB 512   // GEMM block: 8 waves per 128-row tile (occupancy per LDS copy)

typedef __attribute__((ext_vector_type(8))) short          bf8_t;   // 8 x bf16 (4 VGPRs)
typedef __attribute__((ext_vector_type(8))) unsigned short us8_t;
typedef __attribute__((ext_vector_type(4))) float          f4_t;
typedef __attribute__((ext_vector_type(4))) unsigned short us4_t;

__device__ __forceinline__ unsigned short f2bf(float f) {
    union { float f; unsigned u; } v; v.f = f;
    unsigned r = v.u + 0x7FFFu + ((v.u >> 16) & 1u);   // round-to-nearest-even
    return (unsigned short)(r >> 16);
}
__device__ __forceinline__ float bf2f(unsigned short u) {
    union { unsigned u; float f; } v; v.u = (unsigned)u << 16; return v.f;
}

// ---------------- graph build (CSR by dst, rebuilt every call) ----------------

__global__ void k_count(const int* __restrict__ ei, int E, int* __restrict__ cnt) {
    int e = blockIdx.x * TPB + threadIdx.x;
    if (e < E) atomicAdd(&cnt[ei[E + e]], 1);
}

__global__ void k_blocksum(const int* __restrict__ cnt, int n, int* __restrict__ bsum) {
    __shared__ int s[TPB];
    int t = threadIdx.x, i = blockIdx.x * TPB + t;
    s[t] = (i < n) ? cnt[i] : 0;
    __syncthreads();
    for (int off = TPB / 2; off > 0; off >>= 1) {
        if (t < off) s[t] += s[t + off];
        __syncthreads();
    }
    if (t == 0) bsum[blockIdx.x] = s[0];
}

__global__ void k_scan_bsum(int* __restrict__ bsum, int nb) {
    __shared__ int s[512];
    int t = threadIdx.x;
    int v = (t < nb) ? bsum[t] : 0;
    s[t] = v; __syncthreads();
    for (int off = 1; off < 512; off <<= 1) {
        int x = (t >= off) ? s[t - off] : 0;
        __syncthreads();
        s[t] += x;
        __syncthreads();
    }
    if (t < nb) bsum[t] = s[t] - v;   // exclusive block offsets
}

__global__ void k_rowptr(const int* __restrict__ cnt, const int* __restrict__ bsum, int n, int E,
                         int* __restrict__ rowptr, int* __restrict__ cursor,
                         float* __restrict__ dinv, float* __restrict__ dis) {
    __shared__ int s[TPB];
    int t = threadIdx.x, i = blockIdx.x * TPB + t;
    int v = (i < n) ? cnt[i] : 0;
    s[t] = v; __syncthreads();
    for (int off = 1; off < TPB; off <<= 1) {
        int x = (t >= off) ? s[t - off] : 0;
        __syncthreads();
        s[t] += x;
        __syncthreads();
    }
    if (i < n) {
        int start = bsum[blockIdx.x] + s[t] - v;
        rowptr[i] = start;
        cursor[i] = start;
        float d = (float)(v + 1);      // + self loop; deg >= 1 always
        dinv[i] = 1.0f / d;
        dis[i]  = rsqrtf(d);
    }
    if (i == 0) rowptr[n] = E;
}

__global__ void k_fill(const int* __restrict__ ei, int E,
                       int* __restrict__ cursor, int* __restrict__ col) {
    int e = blockIdx.x * TPB + threadIdx.x;
    if (e < E) {
        int src = ei[e], dst = ei[E + e];
        int p = atomicAdd(&cursor[dst], 1);
        col[p] = src;
    }
}

// ---------------- weight transpose+convert: T[m*K + k] = bf16(W[k*M + m]) ----------------
__global__ void k_wconv(const float* W1, const float* Wr1, const float* W2, const float* Wr2,
                        const float* Wmu, const float* Wls,
                        unsigned short* T1, unsigned short* Tr1, unsigned short* T2,
                        unsigned short* Tr2, unsigned short* Tmu, unsigned short* Tls) {
    const float* W; unsigned short* T; int K, M;
    switch (blockIdx.y) {
        case 0: W = W1;  T = T1;  K = 128; M = 96; break;
        case 1: W = Wr1; T = Tr1; K = 128; M = 96; break;
        case 2: W = W2;  T = T2;  K = 96;  M = 64; break;
        case 3: W = Wr2; T = Tr2; K = 96;  M = 64; break;
        case 4: W = Wmu; T = Tmu; K = 64;  M = 32; break;
        default:W = Wls; T = Tls; K = 64;  M = 32; break;
    }
    int idx = blockIdx.x * TPB + threadIdx.x;
    if (idx < K * M) {
        int m = idx / K, k = idx % K;
        T[idx] = f2bf(W[k * M + m]);
    }
}

// ---------------- MFMA GEMM v4: LDS-staged B, 8 waves / 128-row tile ----------------
// A: n x K (fp32 if AF32 else bf16).  WT: M x K bf16.  Yb: n x M bf16.
// B staged once per block into LDS (padded stride ST=K+8); 8 waves share the copy ->
// 24 waves/CU at 52 KB LDS (vs 12 at TPB=256) to hide the A-load + ds_read latency chains.
template <int K, int M, bool AF32>
__global__ __launch_bounds__(GTPB) void k_gemm4(const void* __restrict__ Av,
                                                const unsigned short* __restrict__ WT,
                                                unsigned short* __restrict__ Yb,
                                                int n, int nt) {
    constexpr int KS = K / 32;
    constexpr int ST = K + 8;
    __shared__ unsigned short Bs[M * ST];
    for (int i = threadIdx.x * 8; i < M * K; i += GTPB * 8) {
        int m = i / K, k = i - m * K;
        *(us8_t*)(Bs + m * ST + k) = *(const us8_t*)(WT + i);
    }
    __syncthreads();

    int lane = threadIdx.x & 63;
    int wave = threadIdx.x >> 6;     // 0..7
    int quad = lane >> 4;
    int l15  = lane & 15;

    for (int tile = blockIdx.x; tile < nt; tile += gridDim.x) {
        int base = tile * 128 + wave * 16;
        int rA = base + l15; if (rA > n - 1) rA = n - 1;

        bf8_t a[KS];
        if (AF32) {
            const float* ap = (const float*)Av + (size_t)rA * K + quad * 8;
#pragma unroll
            for (int s = 0; s < KS; s++) {
                f4_t lo = *(const f4_t*)(ap + s * 32);
                f4_t hi = *(const f4_t*)(ap + s * 32 + 4);
                bf8_t t;
                t[0] = (short)f2bf(lo.x); t[1] = (short)f2bf(lo.y);
                t[2] = (short)f2bf(lo.z); t[3] = (short)f2bf(lo.w);
                t[4] = (short)f2bf(hi.x); t[5] = (short)f2bf(hi.y);
                t[6] = (short)f2bf(hi.z); t[7] = (short)f2bf(hi.w);
                a[s] = t;
            }
        } else {
            const unsigned short* ap = (const unsigned short*)Av + (size_t)rA * K + quad * 8;
#pragma unroll
            for (int s = 0; s < KS; s++) a[s] = *(const bf8_t*)(ap + s * 32);
        }

        int row = base + quad * 4;
#pragma unroll
        for (int ct = 0; ct < M / 16; ct++) {
            const unsigned short* bp = Bs + (ct * 16 + l15) * ST + quad * 8;
            f4_t acc = {0.f, 0.f, 0.f, 0.f};
#pragma unroll
            for (int s = 0; s < KS; s++) {
                bf8_t b = *(const bf8_t*)(bp + s * 32);
                acc = __builtin_amdgcn_mfma_f32_16x16x32_bf16(a[s], b, acc, 0, 0, 0);
            }
            int colg = ct * 16 + l15;
#pragma unroll
            for (int r = 0; r < 4; r++) {
                if (row + r < n) Yb[(size_t)(row + r) * M + colg] = f2bf(acc[r]);
            }
        }
    }
}

// ---------------- head GEMM v4: out = Z @ [Wmu|Wls] + bias, fp32, split outputs ----------------
__global__ __launch_bounds__(GTPB) void k_gemm_out4(const unsigned short* __restrict__ Z,
                                                    const unsigned short* __restrict__ WT,
                                                    const float* __restrict__ bmu,
                                                    const float* __restrict__ bls,
                                                    float* __restrict__ out, int n, int nt) {
    constexpr int K = 64, M = 64, KS = 2, ST = K + 8;
    __shared__ unsigned short Bs[M * ST];
    for (int i = threadIdx.x * 8; i < M * K; i += GTPB * 8) {
        int m = i / K, k = i - m * K;
        *(us8_t*)(Bs + m * ST + k) = *(const us8_t*)(WT + i);
    }
    __syncthreads();

    int lane = threadIdx.x & 63;
    int wave = threadIdx.x >> 6;
    int quad = lane >> 4;
    int l15  = lane & 15;

    for (int tile = blockIdx.x; tile < nt; tile += gridDim.x) {
        int base = tile * 128 + wave * 16;
        int rA = base + l15; if (rA > n - 1) rA = n - 1;
        const unsigned short* ap = Z + (size_t)rA * K + quad * 8;
        bf8_t a[KS];
#pragma unroll
        for (int s = 0; s < KS; s++) a[s] = *(const bf8_t*)(ap + s * 32);

        int row = base + quad * 4;
#pragma unroll
        for (int ct = 0; ct < M / 16; ct++) {
            const unsigned short* bp = Bs + (ct * 16 + l15) * ST + quad * 8;
            f4_t acc = {0.f, 0.f, 0.f, 0.f};
#pragma unroll
            for (int s = 0; s < KS; s++) {
                bf8_t b = *(const bf8_t*)(bp + s * 32);
                acc = __builtin_amdgcn_mfma_f32_16x16x32_bf16(a[s], b, acc, 0, 0, 0);
            }
            int colg = ct * 16 + l15;
            float bias = (colg < 32) ? bmu[colg] : bls[colg - 32];
            float* dst = (colg < 32) ? (out + colg) : (out + (size_t)n * 32 + (colg - 32));
#pragma unroll
            for (int r = 0; r < 4; r++) {
                if (row + r < n) dst[(size_t)(row + r) * 32] = acc[r] + bias;
            }
        }
    }
}

// ---------------- ClusterGCN aggregation (bf16 in/out) ----------------
// AB: n x 2*MF bf16 rows [y | r].  Hb[i] = bf16( s * relu( dinv[i]*(sum_{src->i} y[src] + y[i])
//                                                          + r[i] + bias ) ),  s = SCALE?dis[i]:1
template <int MF, int GRP, bool SCALE>
__global__ __launch_bounds__(TPB) void k_aggc(const unsigned short* __restrict__ AB,
                                              const float* __restrict__ bias,
                                              const float* __restrict__ dinv,
                                              const float* __restrict__ dis,
                                              const int* __restrict__ rowptr,
                                              const int* __restrict__ col,
                                              unsigned short* __restrict__ Hb, int n) {
    constexpr int LD = 2 * MF;
    int g = blockIdx.x * (TPB / GRP) + threadIdx.x / GRP;
    int l = threadIdx.x & (GRP - 1);
    if (g >= n) return;
    int c = l * 8;
    if (c >= MF) return;
    int r0 = rowptr[g], r1 = rowptr[g + 1];
    float acc[8];
    {
        bf8_t v = *(const bf8_t*)(AB + (size_t)g * LD + c);
#pragma unroll
        for (int j = 0; j < 8; j++) acc[j] = bf2f((unsigned short)v[j]);
    }
    int e = r0;
    for (; e + 4 <= r1; e += 4) {          // 4-way MLP unroll
        int s0 = col[e], s1 = col[e + 1], s2 = col[e + 2], s3 = col[e + 3];
        bf8_t v0 = *(const bf8_t*)(AB + (size_t)s0 * LD + c);
        bf8_t v1 = *(const bf8_t*)(AB + (size_t)s1 * LD + c);
        bf8_t v2 = *(const bf8_t*)(AB + (size_t)s2 * LD + c);
        bf8_t v3 = *(const bf8_t*)(AB + (size_t)s3 * LD + c);
#pragma unroll
        for (int j = 0; j < 8; j++)
            acc[j] += (bf2f((unsigned short)v0[j]) + bf2f((unsigned short)v1[j]))
                    + (bf2f((unsigned short)v2[j]) + bf2f((unsigned short)v3[j]));
    }
    for (; e < r1; ++e) {
        int s = col[e];
        bf8_t v = *(const bf8_t*)(AB + (size_t)s * LD + c);
#pragma unroll
        for (int j = 0; j < 8; j++) acc[j] += bf2f((unsigned short)v[j]);
    }
    float di = dinv[g];
    float sc = SCALE ? dis[g] : 1.0f;
    bf8_t rr = *(const bf8_t*)(AB + (size_t)g * LD + MF + c);
    us8_t o;
#pragma unroll
    for (int j = 0; j < 8; j++) {
        float h = fmaxf(acc[j] * di + bf2f((unsigned short)rr[j]) + bias[c + j], 0.f);
        o[j] = f2bf(SCALE ? sc * h : h);
    }
    *(us8_t*)(Hb + (size_t)g * MF + c) = o;
}

// ---------------- head aggregation: Z[g] = bf16( dis[g] * (sum_{src->g} H2s[src] + H2s[g]) ) ----
// H2s rows are pre-scaled by dis (written by layer-2 epilogue), so no per-edge dis load.
__global__ __launch_bounds__(TPB) void k_agghead(const unsigned short* __restrict__ H2s,
                                                 const float* __restrict__ dis,
                                                 const int* __restrict__ rowptr,
                                                 const int* __restrict__ col,
                                                 unsigned short* __restrict__ Z, int n) {
    const int GRP = 8;
    int g = blockIdx.x * (TPB / GRP) + threadIdx.x / GRP;
    int l = threadIdx.x & (GRP - 1);
    if (g >= n) return;
    int c = l * 8;
    int r0 = rowptr[g], r1 = rowptr[g + 1];
    float acc[8];
    {
        bf8_t v = *(const bf8_t*)(H2s + (size_t)g * 64 + c);
#pragma unroll
        for (int j = 0; j < 8; j++) acc[j] = bf2f((unsigned short)v[j]);
    }
    int e = r0;
    for (; e + 4 <= r1; e += 4) {
        int s0 = col[e], s1 = col[e + 1], s2 = col[e + 2], s3 = col[e + 3];
        bf8_t v0 = *(const bf8_t*)(H2s + (size_t)s0 * 64 + c);
        bf8_t v1 = *(const bf8_t*)(H2s + (size_t)s1 * 64 + c);
        bf8_t v2 = *(const bf8_t*)(H2s + (size_t)s2 * 64 + c);
        bf8_t v3 = *(const bf8_t*)(H2s + (size_t)s3 * 64 + c);
#pragma unroll
        for (int j = 0; j < 8; j++)
            acc[j] += (bf2f((unsigned short)v0[j]) + bf2f((unsigned short)v1[j]))
                    + (bf2f((unsigned short)v2[j]) + bf2f((unsigned short)v3[j]));
    }
    for (; e < r1; ++e) {
        int s = col[e];
        bf8_t v = *(const bf8_t*)(H2s + (size_t)s * 64 + c);
#pragma unroll
        for (int j = 0; j < 8; j++) acc[j] += bf2f((unsigned short)v[j]);
    }
    float dg = dis[g];
    us8_t o;
#pragma unroll
    for (int j = 0; j < 8; j++) o[j] = f2bf(dg * acc[j]);
    *(us8_t*)(Z + (size_t)g * 64 + c) = o;
}

// ---------------- launch ----------------

extern "C" void kernel_launch(void* const* d_in, const int* in_sizes, int n_in,
                              void* d_out, int out_size, void* d_ws, size_t ws_size,
                              hipStream_t stream) {
    const float* x   = (const float*)d_in[0];
    const int*   ei  = (const int*)d_in[1];
    const float* W1  = (const float*)d_in[2];
    const float* b1  = (const float*)d_in[3];
    const float* Wr1 = (const float*)d_in[4];
    const float* W2  = (const float*)d_in[5];
    const float* b2  = (const float*)d_in[6];
    const float* Wr2 = (const float*)d_in[7];
    const float* Wmu = (const float*)d_in[8];
    const float* bmu = (const float*)d_in[9];
    const float* Wls = (const float*)d_in[10];
    const float* bls = (const float*)d_in[11];
    float* out = (float*)d_out;

    const int IN = 128, L1F = 96, L2F = 64;
    const int N = in_sizes[0] / IN;
    const int E = in_sizes[1] / 2;

    char* ws = (char*)d_ws;
    size_t off = 0;
    auto alloc = [&](size_t b) { size_t r = off; off += (b + 255) & ~(size_t)255; return r; };

    const int nb = (N + TPB - 1) / TPB;
    int*   cnt  = (int*)(ws + alloc((size_t)N * 4));
    int*   bsum = (int*)(ws + alloc((size_t)nb * 4));
    int*   rowp = (int*)(ws + alloc((size_t)(N + 1) * 4));
    int*   curs = (int*)(ws + alloc((size_t)N * 4));
    int*   col  = (int*)(ws + alloc((size_t)E * 4));
    float* dinv = (float*)(ws + alloc((size_t)N * 4));
    float* dis  = (float*)(ws + alloc((size_t)N * 4));
    // weight blocks allocated contiguously -> concatenated [W|Wr] views (all sizes %256==0)
    unsigned short* T1  = (unsigned short*)(ws + alloc((size_t)IN  * L1F * 2));
    unsigned short* Tr1 = (unsigned short*)(ws + alloc((size_t)IN  * L1F * 2));
    unsigned short* T2  = (unsigned short*)(ws + alloc((size_t)L1F * L2F * 2));
    unsigned short* Tr2 = (unsigned short*)(ws + alloc((size_t)L1F * L2F * 2));
    unsigned short* Tmu = (unsigned short*)(ws + alloc((size_t)L2F * 32 * 2));
    unsigned short* Tls = (unsigned short*)(ws + alloc((size_t)L2F * 32 * 2));
    unsigned short* AB1 = (unsigned short*)(ws + alloc((size_t)N * 2 * L1F * 2)); // N x 192 bf16
    unsigned short* AB2 = (unsigned short*)(ws + alloc((size_t)N * 2 * L2F * 2)); // N x 128 bf16
    unsigned short* Hb1 = (unsigned short*)(ws + alloc((size_t)N * L1F * 2));     // relu'd h1
    unsigned short* H2s = (unsigned short*)(ws + alloc((size_t)N * L2F * 2));     // dis-scaled h2
    unsigned short* Zag = (unsigned short*)(ws + alloc((size_t)N * L2F * 2));     // aggregated head input

    hipMemsetAsync(cnt, 0, (size_t)N * 4, stream);

    dim3 eg((E + TPB - 1) / TPB);
    k_count<<<eg, TPB, 0, stream>>>(ei, E, cnt);
    k_blocksum<<<nb, TPB, 0, stream>>>(cnt, N, bsum);
    k_scan_bsum<<<1, 512, 0, stream>>>(bsum, nb);
    k_rowptr<<<nb, TPB, 0, stream>>>(cnt, bsum, N, E, rowp, curs, dinv, dis);
    k_fill<<<eg, TPB, 0, stream>>>(ei, E, curs, col);

    k_wconv<<<dim3(48, 6), TPB, 0, stream>>>(W1, Wr1, W2, Wr2, Wmu, Wls,
                                             T1, Tr1, T2, Tr2, Tmu, Tls);

    const int nt = (N + 127) / 128;   // 128-row tiles (8 waves x 16 rows)
    // layer 1: AB1 = x @ [W1|Wr1] (fused fp32->bf16 on A), Hb1 = relu(dinv*agg(y) + r + b1)
    k_gemm4<128, 192, true><<<768, GTPB, 0, stream>>>(x, T1, AB1, N, nt);
    k_aggc<96, 16, false><<<(N + 15) / 16, TPB, 0, stream>>>(AB1, b1, dinv, dis, rowp, col, Hb1, N);

    // layer 2: AB2 = h1 @ [W2|Wr2], H2s = dis * relu(dinv*agg(y) + r + b2)
    k_gemm4<96, 128, false><<<768, GTPB, 0, stream>>>(Hb1, T2, AB2, N, nt);
    k_aggc<64, 8, true><<<(N + 31) / 32, TPB, 0, stream>>>(AB2, b2, dinv, dis, rowp, col, H2s, N);

    // heads: Zag = dis * (agg H2s + H2s), out = Zag @ [Wmu|Wls] + bias
    k_agghead<<<(N + 31) / 32, TPB, 0, stream>>>(H2s, dis, rowp, col, Zag, N);
    k_gemm_out4<<<768, GTPB, 0, stream>>>(Zag, Tmu, bmu, bls, out, N, nt);
}